// Round 2
// baseline (323.219 us; speedup 1.0000x reference)
//
#include <hip/hip_runtime.h>

// Problem constants (TextEncoder_55671366091616)
#define BB 32
#define SS 2048
#define DD 1024
#define EE 64
#define KK 8
#define TT 128            // N_TAGS
#define MM (BB * EE)      // 2048 output rows

typedef __attribute__((ext_vector_type(8))) short short8;   // bf16x8 frag
typedef __attribute__((ext_vector_type(4))) float f32x4;    // MFMA accumulator

__device__ __forceinline__ unsigned short f2bf(float f) {
    union { float f; unsigned int u; } v; v.f = f;
    unsigned int u = v.u + 0x7FFFu + ((v.u >> 16) & 1u);
    return (unsigned short)(u >> 16);
}

// ws layout (bf16 elems): A_pool [2048][1024] at 0 (4 MB), W_bf16 [128][1024] at +4 MB
#define W_OFF ((size_t)MM * DD)

// ---------------------------------------------------------------------------
// Kernel 1: gather + mean-pool -> A_bf16, plus one-time W fp32->bf16 convert.
// grid = 1024 + 16 blocks, 256 threads, zero LDS -> high occupancy.
// Blocks < 1024: one wave per (entity, D-half). Each selected hs row is read
//   ONCE as a fully-coalesced 2-KB segment (vs round-1's 8x 512-B slices).
//   Masked entities (e >= num_entities) skip all loads (wave-uniform branch).
// Blocks >= 1024: convert fc_w (128x1024 fp32) to bf16 once (round 1 did this
//   per-block: 512 x 64 KB).
// ---------------------------------------------------------------------------
__global__ __launch_bounds__(256) void pool_kernel(
    const float* __restrict__ hs,        // [B,S,D]
    const int*   __restrict__ subw_idx,  // [B,E,K]
    const int*   __restrict__ subw_cnt,  // [B,E]
    const int*   __restrict__ num_ent,   // [B]
    const float* __restrict__ fc_w,      // [T,D]
    unsigned short* __restrict__ wsb)    // bf16 workspace
{
    const int t = threadIdx.x;
    if (blockIdx.x < 1024) {
        const int wave = t >> 6;
        const int lane = t & 63;
        const int gid  = blockIdx.x * 4 + wave;   // 0..4095 = (entity, half)
        const int be   = gid >> 1;                // 0..2047
        const int half = gid & 1;
        const int b = be >> 6;
        const int e = be & 63;
        const int ne = num_ent[b];

        unsigned short* outp = wsb + (size_t)be * DD + half * 512 + lane * 8;

        if (e >= ne) {                    // wave-uniform: masked entity
            ushort4 z = {0, 0, 0, 0};
            *(ushort4*)(outp)     = z;
            *(ushort4*)(outp + 4) = z;
            return;
        }

        const int cnt = subw_cnt[be];
        const float scale = 1.0f / (float)cnt;
        const int4* ip = (const int4*)(subw_idx + (size_t)be * KK);
        const int4 i0 = ip[0];
        const int4 i1 = ip[1];
        const int idx[8] = { i0.x, i0.y, i0.z, i0.w, i1.x, i1.y, i1.z, i1.w };

        const float* base = hs + (size_t)b * SS * DD + half * 512 + lane * 8;

        // Issue all 16 row-segment loads up front (masked slots re-read
        // idx[0]'s segment -> L1 hit, weight 0 below). Fully independent.
        float4 v[8][2];
        #pragma unroll
        for (int k = 0; k < 8; ++k) {
            const int s = (k < cnt) ? idx[k] : idx[0];
            const float4* p = (const float4*)(base + (size_t)s * DD);
            v[k][0] = p[0];
            v[k][1] = p[1];
        }

        float acc[8];
        #pragma unroll
        for (int j = 0; j < 8; ++j) acc[j] = 0.f;
        #pragma unroll
        for (int k = 0; k < 8; ++k) {
            const float w = (k < cnt) ? 1.0f : 0.0f;
            acc[0] = fmaf(w, v[k][0].x, acc[0]);
            acc[1] = fmaf(w, v[k][0].y, acc[1]);
            acc[2] = fmaf(w, v[k][0].z, acc[2]);
            acc[3] = fmaf(w, v[k][0].w, acc[3]);
            acc[4] = fmaf(w, v[k][1].x, acc[4]);
            acc[5] = fmaf(w, v[k][1].y, acc[5]);
            acc[6] = fmaf(w, v[k][1].z, acc[6]);
            acc[7] = fmaf(w, v[k][1].w, acc[7]);
        }

        ushort4 o0, o1;
        o0.x = f2bf(acc[0] * scale); o0.y = f2bf(acc[1] * scale);
        o0.z = f2bf(acc[2] * scale); o0.w = f2bf(acc[3] * scale);
        o1.x = f2bf(acc[4] * scale); o1.y = f2bf(acc[5] * scale);
        o1.z = f2bf(acc[6] * scale); o1.w = f2bf(acc[7] * scale);
        *(ushort4*)(outp)     = o0;
        *(ushort4*)(outp + 4) = o1;
    } else {
        // W convert: 16 blocks x 256 threads x 32 floats = 128*1024
        const int wb  = blockIdx.x - 1024;        // 0..15
        const int row = wb * 8 + (t >> 5);        // 0..127
        const int col = (t & 31) * 32;
        const float4* src = (const float4*)(fc_w + (size_t)row * DD + col);
        unsigned short* dst = wsb + W_OFF + (size_t)row * DD + col;
        #pragma unroll
        for (int j = 0; j < 8; ++j) {
            float4 x = src[j];
            ushort4 o;
            o.x = f2bf(x.x); o.y = f2bf(x.y); o.z = f2bf(x.z); o.w = f2bf(x.w);
            *(ushort4*)(dst + j * 4) = o;
        }
    }
}

// ---------------------------------------------------------------------------
// Kernel 2: C[2048x128] = A_bf16 * W_bf16^T + bias. Direct store (no atomics,
// no partials). 64 blocks (M-tile 32, N full 128), 4 waves, K-step 64.
// LDS 23 KB, row stride 72 shorts (36 dw): 2-way bank alias max = free.
// Wave w: M-sub (w&1)*16, N-base (w>>1)*64; 8 MFMAs/iter, 128 total.
// ---------------------------------------------------------------------------
#define LSTR2 72

__global__ __launch_bounds__(256) void gemm_kernel(
    const unsigned short* __restrict__ wsb,
    const float* __restrict__ fc_b,   // [T]
    float* __restrict__ out)          // [M,T]
{
    __shared__ unsigned short As[32][LSTR2];   // 4.6 KB
    __shared__ unsigned short Ws[TT][LSTR2];   // 18.4 KB

    const int t    = threadIdx.x;
    const int wid  = t >> 6;
    const int lane = t & 63;
    const int mbase = blockIdx.x * 32;

    const int msub  = (wid & 1) * 16;
    const int nbase = (wid >> 1) * 64;
    const int lm = lane & 15;
    const int lq = (lane >> 4) * 8;

    // staging coords
    const int ar = t >> 3;            // 0..31
    const int ac = (t & 7) * 8;       // 0..56
    const int wr = t >> 1;            // 0..127
    const int wc = (t & 1) * 32;      // 0 / 32

    f32x4 acc0 = {0.f,0.f,0.f,0.f}, acc1 = {0.f,0.f,0.f,0.f};
    f32x4 acc2 = {0.f,0.f,0.f,0.f}, acc3 = {0.f,0.f,0.f,0.f};

    const unsigned short* Ag = wsb + (size_t)(mbase + ar) * DD + ac;
    const unsigned short* Wg = wsb + W_OFF + (size_t)wr * DD + wc;

    for (int kt = 0; kt < DD / 64; ++kt) {
        const int k0 = kt * 64;
        *(short8*)&As[ar][ac] = *(const short8*)(Ag + k0);
        #pragma unroll
        for (int j = 0; j < 4; ++j)
            *(short8*)&Ws[wr][wc + 8 * j] = *(const short8*)(Wg + k0 + 8 * j);
        __syncthreads();

        #pragma unroll
        for (int ksub = 0; ksub < 2; ++ksub) {
            const int kc = ksub * 32 + lq;
            short8 a  = *(const short8*)&As[msub + lm][kc];
            short8 b0 = *(const short8*)&Ws[nbase +  0 + lm][kc];
            short8 b1 = *(const short8*)&Ws[nbase + 16 + lm][kc];
            short8 b2 = *(const short8*)&Ws[nbase + 32 + lm][kc];
            short8 b3 = *(const short8*)&Ws[nbase + 48 + lm][kc];
            acc0 = __builtin_amdgcn_mfma_f32_16x16x32_bf16(a, b0, acc0, 0, 0, 0);
            acc1 = __builtin_amdgcn_mfma_f32_16x16x32_bf16(a, b1, acc1, 0, 0, 0);
            acc2 = __builtin_amdgcn_mfma_f32_16x16x32_bf16(a, b2, acc2, 0, 0, 0);
            acc3 = __builtin_amdgcn_mfma_f32_16x16x32_bf16(a, b3, acc3, 0, 0, 0);
        }
        __syncthreads();
    }

    // D layout: lane holds D[row=(lane>>4)*4 + r][col=lane&15]
    const int mrow = mbase + msub + (lane >> 4) * 4;
    const int ncol = nbase + lm;
    const float bb0 = fc_b[ncol +  0];
    const float bb1 = fc_b[ncol + 16];
    const float bb2 = fc_b[ncol + 32];
    const float bb3 = fc_b[ncol + 48];
    #pragma unroll
    for (int r = 0; r < 4; ++r) {
        const size_t base = (size_t)(mrow + r) * TT + ncol;
        out[base +  0] = acc0[r] + bb0;
        out[base + 16] = acc1[r] + bb1;
        out[base + 32] = acc2[r] + bb2;
        out[base + 48] = acc3[r] + bb3;
    }
}

extern "C" void kernel_launch(void* const* d_in, const int* in_sizes, int n_in,
                              void* d_out, int out_size, void* d_ws, size_t ws_size,
                              hipStream_t stream) {
    const float* hs       = (const float*)d_in[0];
    const int*   subw_idx = (const int*)  d_in[1];
    const int*   subw_cnt = (const int*)  d_in[2];
    const int*   num_ent  = (const int*)  d_in[3];
    const float* fc_w     = (const float*)d_in[4];
    const float* fc_b     = (const float*)d_in[5];
    float*       out      = (float*)d_out;
    unsigned short* wsb   = (unsigned short*)d_ws;

    pool_kernel<<<1024 + 16, 256, 0, stream>>>(
        hs, subw_idx, subw_cnt, num_ent, fc_w, wsb);
    gemm_kernel<<<MM / 32, 256, 0, stream>>>(wsb, fc_b, out);
}